// Round 2
// baseline (549.987 us; speedup 1.0000x reference)
//
#include <hip/hip_runtime.h>
#include <stdint.h>

#define NN 50000
#define NE 800000
#define FD 64
#define HD 128

// ---------- bf16 helpers (storage = unsigned short / packed uint) ----------
__device__ __forceinline__ float bflo(unsigned int v) {
    union { unsigned int u; float f; } c; c.u = v << 16; return c.f;
}
__device__ __forceinline__ float bfhi(unsigned int v) {
    union { unsigned int u; float f; } c; c.u = v & 0xffff0000u; return c.f;
}
__device__ __forceinline__ unsigned short f2bf(float f) {
    union { float f; unsigned int u; } c; c.f = f;
    unsigned int u = c.u;
    return (unsigned short)((u + 0x7fffu + ((u >> 16) & 1u)) >> 16);
}
__device__ __forceinline__ unsigned int pack2(float a, float b) {
    return (unsigned int)f2bf(a) | ((unsigned int)f2bf(b) << 16);
}

// ---------- graph prep kernels ----------
__global__ void hist_k(const int* __restrict__ dst, int* __restrict__ cnt, int n) {
    int g = blockIdx.x * 256 + threadIdx.x;
    if (g < n) atomicAdd(&cnt[dst[g]], 1);
}

__global__ void dinv_k(const int* __restrict__ cnt, float* __restrict__ dinv, int n) {
    int g = blockIdx.x * 256 + threadIdx.x;
    if (g < n) dinv[g] = rsqrtf((float)(cnt[g] + 1));  // +1 self-loop
}

__global__ void scanA_k(const int* __restrict__ cnt, int* __restrict__ off,
                        int* __restrict__ bsum, int n) {
    __shared__ int sh[256];
    int t = threadIdx.x;
    int g = blockIdx.x * 256 + t;
    int v = (g < n) ? cnt[g] : 0;
    sh[t] = v; __syncthreads();
    for (int d = 1; d < 256; d <<= 1) {
        int x = (t >= d) ? sh[t - d] : 0; __syncthreads();
        sh[t] += x; __syncthreads();
    }
    if (g < n) off[g] = sh[t] - v;            // exclusive within block
    if (t == 255) bsum[blockIdx.x] = sh[255]; // block total
}

__global__ void scanB_k(int* __restrict__ bsum, int nb) {
    __shared__ int sh[256];
    int t = threadIdx.x;
    int v = (t < nb) ? bsum[t] : 0;
    sh[t] = v; __syncthreads();
    for (int d = 1; d < 256; d <<= 1) {
        int x = (t >= d) ? sh[t - d] : 0; __syncthreads();
        sh[t] += x; __syncthreads();
    }
    if (t < nb) bsum[t] = sh[t] - v;          // exclusive
}

__global__ void scanC_k(int* __restrict__ off, const int* __restrict__ bsum,
                        int n, int total) {
    int g = blockIdx.x * 256 + threadIdx.x;
    if (g < n) off[g] += bsum[g >> 8];
    if (g == 0) off[n] = total;
}

__global__ void fill_k(const int* __restrict__ src, const int* __restrict__ dst,
                       const int* __restrict__ off, int* __restrict__ cur,
                       int* __restrict__ csr, int n) {
    int g = blockIdx.x * 256 + threadIdx.x;
    if (g < n) {
        int d = dst[g];
        int p = atomicAdd(&cur[d], 1);
        csr[off[d] + p] = src[g];
    }
}

// ---------- GEMM: out[N,COLS] = epi(A[N,K] @ W[K,COLS] * rowscale + bias) ----------
// A: fp32 (A_F32) or packed bf16; W/bias: fp32 global, bf16 in LDS; out: bf16 packed or fp32.
// EPI: 0 = none, 1 = relu, 2 = sigmoid
template <int K, int COLS, int EPI, bool BIAS, bool RSCALE, bool A_F32, bool OUT_F32>
__global__ __launch_bounds__(256) void gemm_k(
    const void* __restrict__ Av,
    const float* __restrict__ W,
    const float* __restrict__ bias,
    const float* __restrict__ dinv,
    void* __restrict__ outv, int nrows)
{
    constexpr int CPT = COLS / 32;  // cols per thread (4 or 2)
    static_assert(CPT == 2 || CPT == 4, "CPT");
    constexpr int AP = 72;          // ushort stride for At rows: 144 B, 16B-multiple
    __shared__ unsigned short At[K * AP];   // A^T tile, bf16: At[k][r]
    __shared__ unsigned short Ws[K * COLS]; // W, bf16: Ws[k][c]

    const int tid = threadIdx.x;
    const int row0 = blockIdx.x * 64;

    // stage W: fp32 global -> bf16 LDS
    {
        const float4* Wg = (const float4*)W;
        uint2* Wl = (uint2*)Ws;
        for (int i = tid; i < K * COLS / 4; i += 256) {
            float4 w = Wg[i];
            uint2 p; p.x = pack2(w.x, w.y); p.y = pack2(w.z, w.w);
            Wl[i] = p;
        }
    }
    // stage A transposed: At[k][r] bf16
    if constexpr (A_F32) {
        const float* A = (const float*)Av;
        for (int i = tid; i < 64 * (K / 4); i += 256) {
            int r = i & 63, kv = i >> 6;
            int row = row0 + r;
            float4 v = make_float4(0.f, 0.f, 0.f, 0.f);
            if (row < nrows) v = *(const float4*)(A + (size_t)row * K + kv * 4);
            int kb = kv * 4;
            At[(kb + 0) * AP + r] = f2bf(v.x);
            At[(kb + 1) * AP + r] = f2bf(v.y);
            At[(kb + 2) * AP + r] = f2bf(v.z);
            At[(kb + 3) * AP + r] = f2bf(v.w);
        }
    } else {
        const unsigned short* A = (const unsigned short*)Av;
        for (int i = tid; i < 64 * (K / 8); i += 256) {
            int r = i & 63, kv = i >> 6;
            int row = row0 + r;
            uint4 v = make_uint4(0u, 0u, 0u, 0u);
            if (row < nrows) v = *(const uint4*)(A + (size_t)row * K + kv * 8);
            int kb = kv * 8;
            At[(kb + 0) * AP + r] = (unsigned short)(v.x & 0xffffu);
            At[(kb + 1) * AP + r] = (unsigned short)(v.x >> 16);
            At[(kb + 2) * AP + r] = (unsigned short)(v.y & 0xffffu);
            At[(kb + 3) * AP + r] = (unsigned short)(v.y >> 16);
            At[(kb + 4) * AP + r] = (unsigned short)(v.z & 0xffffu);
            At[(kb + 5) * AP + r] = (unsigned short)(v.z >> 16);
            At[(kb + 6) * AP + r] = (unsigned short)(v.w & 0xffffu);
            At[(kb + 7) * AP + r] = (unsigned short)(v.w >> 16);
        }
    }
    __syncthreads();

    const int tx = tid & 31, ty = tid >> 5; // 32 col-groups x 8 row-groups
    float acc[8][CPT];
    #pragma unroll
    for (int i = 0; i < 8; i++)
        #pragma unroll
        for (int j = 0; j < CPT; j++) acc[i][j] = 0.f;

    #pragma unroll 2
    for (int k = 0; k < K; k++) {
        uint4 ap = *(const uint4*)&At[k * AP + ty * 8]; // 8 rows' bf16 at feature k
        float a[8] = { bflo(ap.x), bfhi(ap.x), bflo(ap.y), bfhi(ap.y),
                       bflo(ap.z), bfhi(ap.z), bflo(ap.w), bfhi(ap.w) };
        float w[CPT];
        if constexpr (CPT == 4) {
            uint2 wv = *(const uint2*)&Ws[k * COLS + tx * 4];
            w[0] = bflo(wv.x); w[1] = bfhi(wv.x);
            w[2] = bflo(wv.y); w[3] = bfhi(wv.y);
        } else {
            unsigned int wv = *(const unsigned int*)&Ws[k * COLS + tx * 2];
            w[0] = bflo(wv); w[1] = bfhi(wv);
        }
        #pragma unroll
        for (int i = 0; i < 8; i++)
            #pragma unroll
            for (int j = 0; j < CPT; j++)
                acc[i][j] = fmaf(a[i], w[j], acc[i][j]);
    }

    // epilogue
    float bv[CPT];
    #pragma unroll
    for (int j = 0; j < CPT; j++) bv[j] = BIAS ? bias[tx * CPT + j] : 0.f;

    #pragma unroll
    for (int i = 0; i < 8; i++) {
        int row = row0 + ty * 8 + i;
        if (row < nrows) {
            float sc = RSCALE ? dinv[row] : 1.f;
            float v[CPT];
            #pragma unroll
            for (int j = 0; j < CPT; j++) {
                float t = fmaf(acc[i][j], sc, bv[j]);
                if (EPI == 1) t = fmaxf(t, 0.f);
                if (EPI == 2) t = 1.f / (1.f + __expf(-t));
                v[j] = t;
            }
            if constexpr (OUT_F32) {
                float* op = (float*)outv + (size_t)row * COLS + tx * CPT;
                if constexpr (CPT == 4) {
                    *(float4*)op = make_float4(v[0], v[1], v[2], v[3]);
                } else {
                    *(float2*)op = make_float2(v[0], v[1]);
                }
            } else {
                unsigned short* op = (unsigned short*)outv + (size_t)row * COLS + tx * CPT;
                if constexpr (CPT == 4) {
                    uint2 p; p.x = pack2(v[0], v[1]); p.y = pack2(v[2], v[3]);
                    *(uint2*)op = p;
                } else {
                    *(unsigned int*)op = pack2(v[0], v[1]);
                }
            }
        }
    }
}

// ---------- GCN aggregation: out[d] = relu(dinv[d]*(hws[d] + sum_in hws[s]) + b) ----------
// hws = (h@W)*dinv[row], packed bf16x2. One wave per node; lane owns features {2l, 2l+1}.
__global__ __launch_bounds__(256) void agg_k(
    const unsigned int* __restrict__ hws,  // [N][64] bf16x2
    const int* __restrict__ off, const int* __restrict__ csr,
    const float* __restrict__ dinv, const float* __restrict__ bias,
    unsigned int* __restrict__ out, int n)
{
    int node = blockIdx.x * 4 + (threadIdx.x >> 6);
    if (node >= n) return;
    int lane = threadIdx.x & 63;

    unsigned int v = hws[node * 64 + lane]; // self-loop term
    float s0 = bflo(v), s1 = bfhi(v);

    int b = off[node], e = off[node + 1];
    int j = b;
    for (; j + 4 <= e; j += 4) {
        int i0 = csr[j], i1 = csr[j + 1], i2 = csr[j + 2], i3 = csr[j + 3];
        unsigned int v0 = hws[i0 * 64 + lane];
        unsigned int v1 = hws[i1 * 64 + lane];
        unsigned int v2 = hws[i2 * 64 + lane];
        unsigned int v3 = hws[i3 * 64 + lane];
        s0 += bflo(v0); s1 += bfhi(v0);
        s0 += bflo(v1); s1 += bfhi(v1);
        s0 += bflo(v2); s1 += bfhi(v2);
        s0 += bflo(v3); s1 += bfhi(v3);
    }
    for (; j < e; j++) {
        unsigned int vv = hws[csr[j] * 64 + lane];
        s0 += bflo(vv); s1 += bfhi(vv);
    }

    float di = dinv[node];
    float b0 = bias[2 * lane];
    float b1 = bias[2 * lane + 1];
    float r0 = fmaxf(fmaf(di, s0, b0), 0.f);
    float r1 = fmaxf(fmaf(di, s1, b1), 0.f);
    out[node * 64 + lane] = pack2(r0, r1);
}

// ---------- launch ----------
extern "C" void kernel_launch(void* const* d_in, const int* in_sizes, int n_in,
                              void* d_out, int out_size, void* d_ws, size_t ws_size,
                              hipStream_t stream)
{
    const float* x      = (const float*)d_in[0];
    const int*   ei     = (const int*)d_in[1];
    const float* enc_w1 = (const float*)d_in[2];
    const float* enc_b1 = (const float*)d_in[3];
    const float* enc_w2 = (const float*)d_in[4];
    const float* enc_b2 = (const float*)d_in[5];
    const float* w_c1   = (const float*)d_in[6];
    const float* b_c1   = (const float*)d_in[7];
    const float* w_c2   = (const float*)d_in[8];
    const float* b_c2   = (const float*)d_in[9];
    const float* w_c3   = (const float*)d_in[10];
    const float* b_c3   = (const float*)d_in[11];
    const float* dec_w1 = (const float*)d_in[12];
    const float* dec_b1 = (const float*)d_in[13];
    const float* dec_w2 = (const float*)d_in[14];
    const float* dec_b2 = (const float*)d_in[15];

    const int* src = ei;
    const int* dst = ei + NE;

    char* ws = (char*)d_ws;
    size_t o = 0;
    auto alloc = [&](size_t bytes) -> void* {
        void* p = ws + o;
        o = (o + bytes + 255) & ~(size_t)255;
        return p;
    };
    int*   cnt  = (int*)alloc((size_t)NN * 4);
    int*   cur  = (int*)alloc((size_t)NN * 4);
    int*   off  = (int*)alloc((size_t)(NN + 1) * 4);
    int*   bsum = (int*)alloc(256 * 4);
    int*   csr  = (int*)alloc((size_t)NE * 4);
    float* dinv = (float*)alloc((size_t)NN * 4);
    unsigned short* bufA = (unsigned short*)alloc((size_t)NN * HD * 2);
    unsigned short* bufB = (unsigned short*)alloc((size_t)NN * HD * 2);
    (void)ws_size; (void)n_in; (void)in_sizes; (void)out_size;

    hipMemsetAsync(cnt, 0, (size_t)NN * 4, stream);
    hipMemsetAsync(cur, 0, (size_t)NN * 4, stream);

    const int EB = (NE + 255) / 256;
    const int NB = (NN + 255) / 256;  // 196
    hist_k<<<EB, 256, 0, stream>>>(dst, cnt, NE);
    dinv_k<<<NB, 256, 0, stream>>>(cnt, dinv, NN);
    scanA_k<<<NB, 256, 0, stream>>>(cnt, off, bsum, NN);
    scanB_k<<<1, 256, 0, stream>>>(bsum, NB);
    scanC_k<<<NB, 256, 0, stream>>>(off, bsum, NN, NE);
    fill_k<<<EB, 256, 0, stream>>>(src, dst, off, cur, csr, NE);

    const int GB = (NN + 63) / 64;    // 782 row-tiles
    const int AB = (NN + 3) / 4;      // 12500 agg blocks

    // encoder: h = relu(x@W1+b1) @ W2 + b2   (bf16 intermediates)
    gemm_k<64, 128, 1, true, false, true, false><<<GB, 256, 0, stream>>>(x, enc_w1, enc_b1, nullptr, bufA, NN);
    gemm_k<128, 128, 0, true, false, false, false><<<GB, 256, 0, stream>>>(bufA, enc_w2, enc_b2, nullptr, bufB, NN);
    // conv1: hws = (h@Wc)*dinv ; agg
    gemm_k<128, 128, 0, false, true, false, false><<<GB, 256, 0, stream>>>(bufB, w_c1, nullptr, dinv, bufA, NN);
    agg_k<<<AB, 256, 0, stream>>>((const unsigned int*)bufA, off, csr, dinv, b_c1, (unsigned int*)bufB, NN);
    // conv2
    gemm_k<128, 128, 0, false, true, false, false><<<GB, 256, 0, stream>>>(bufB, w_c2, nullptr, dinv, bufA, NN);
    agg_k<<<AB, 256, 0, stream>>>((const unsigned int*)bufA, off, csr, dinv, b_c2, (unsigned int*)bufB, NN);
    // conv3
    gemm_k<128, 128, 0, false, true, false, false><<<GB, 256, 0, stream>>>(bufB, w_c3, nullptr, dinv, bufA, NN);
    agg_k<<<AB, 256, 0, stream>>>((const unsigned int*)bufA, off, csr, dinv, b_c3, (unsigned int*)bufB, NN);
    // decoder: out = sigmoid(relu(h@W1+b1)@W2+b2), fp32 output
    gemm_k<128, 128, 1, true, false, false, false><<<GB, 256, 0, stream>>>(bufB, dec_w1, dec_b1, nullptr, bufA, NN);
    gemm_k<128, 64, 2, true, false, false, true><<<GB, 256, 0, stream>>>(bufA, dec_w2, dec_b2, nullptr, d_out, NN);
}

// Round 3
// 442.820 us; speedup vs baseline: 1.2420x; 1.2420x over previous
//
#include <hip/hip_runtime.h>
#include <stdint.h>

#define NN 50000
#define NE 800000
#define FD 64
#define HD 128

typedef __attribute__((ext_vector_type(8))) short short8;   // 8 bf16 (4 VGPRs)
typedef __attribute__((ext_vector_type(4))) float f32x4;    // MFMA acc

// ---------- bf16 helpers ----------
__device__ __forceinline__ float bflo(unsigned int v) {
    union { unsigned int u; float f; } c; c.u = v << 16; return c.f;
}
__device__ __forceinline__ float bfhi(unsigned int v) {
    union { unsigned int u; float f; } c; c.u = v & 0xffff0000u; return c.f;
}
__device__ __forceinline__ unsigned short f2bf(float f) {
    union { float f; unsigned int u; } c; c.f = f;
    unsigned int u = c.u;
    return (unsigned short)((u + 0x7fffu + ((u >> 16) & 1u)) >> 16);
}
__device__ __forceinline__ unsigned int pack2(float a, float b) {
    return (unsigned int)f2bf(a) | ((unsigned int)f2bf(b) << 16);
}

// ---------- graph prep ----------
__global__ void hist_k(const int* __restrict__ dst, int* __restrict__ cnt, int n) {
    int g = blockIdx.x * 256 + threadIdx.x;
    if (g < n) atomicAdd(&cnt[dst[g]], 1);
}

__global__ void dinv_k(const int* __restrict__ cnt, float* __restrict__ dinv, int n) {
    int g = blockIdx.x * 256 + threadIdx.x;
    if (g < n) dinv[g] = rsqrtf((float)(cnt[g] + 1));
}

__global__ void scanA_k(const int* __restrict__ cnt, int* __restrict__ off,
                        int* __restrict__ bsum, int n) {
    __shared__ int sh[256];
    int t = threadIdx.x;
    int g = blockIdx.x * 256 + t;
    int v = (g < n) ? cnt[g] : 0;
    sh[t] = v; __syncthreads();
    for (int d = 1; d < 256; d <<= 1) {
        int x = (t >= d) ? sh[t - d] : 0; __syncthreads();
        sh[t] += x; __syncthreads();
    }
    if (g < n) off[g] = sh[t] - v;
    if (t == 255) bsum[blockIdx.x] = sh[255];
}

__global__ void scanB_k(int* __restrict__ bsum, int nb) {
    __shared__ int sh[256];
    int t = threadIdx.x;
    int v = (t < nb) ? bsum[t] : 0;
    sh[t] = v; __syncthreads();
    for (int d = 1; d < 256; d <<= 1) {
        int x = (t >= d) ? sh[t - d] : 0; __syncthreads();
        sh[t] += x; __syncthreads();
    }
    if (t < nb) bsum[t] = sh[t] - v;
}

__global__ void scanC_k(int* __restrict__ off, const int* __restrict__ bsum,
                        int n, int total) {
    int g = blockIdx.x * 256 + threadIdx.x;
    if (g < n) off[g] += bsum[g >> 8];
    if (g == 0) off[n] = total;
}

__global__ void fill_k(const int* __restrict__ src, const int* __restrict__ dst,
                       const int* __restrict__ off, int* __restrict__ cur,
                       int* __restrict__ csr, int n) {
    int g = blockIdx.x * 256 + threadIdx.x;
    if (g < n) {
        int d = dst[g];
        int p = atomicAdd(&cur[d], 1);
        csr[off[d] + p] = src[g];
    }
}

// ---------- weight transpose+convert: W[K][C] fp32 -> Wt[C][K] bf16 ----------
// fixed segmentation: b<32: w0 (64x128); b<96:w1; <160:w2; <224:w3; <288:w4; <352:w5 (128x128); <384:w6 (128x64)
__global__ void wt_k(const float* __restrict__ w0, const float* __restrict__ w1,
                     const float* __restrict__ w2, const float* __restrict__ w3,
                     const float* __restrict__ w4, const float* __restrict__ w5,
                     const float* __restrict__ w6,
                     unsigned short* __restrict__ t0, unsigned short* __restrict__ t1,
                     unsigned short* __restrict__ t2, unsigned short* __restrict__ t3,
                     unsigned short* __restrict__ t4, unsigned short* __restrict__ t5,
                     unsigned short* __restrict__ t6)
{
    int b = blockIdx.x;
    const float* W; unsigned short* T; int K, C;
    if      (b <  32) { W = w0; T = t0; K =  64; C = 128; }
    else if (b <  96) { W = w1; T = t1; K = 128; C = 128; b -= 32; }
    else if (b < 160) { W = w2; T = t2; K = 128; C = 128; b -= 96; }
    else if (b < 224) { W = w3; T = t3; K = 128; C = 128; b -= 160; }
    else if (b < 288) { W = w4; T = t4; K = 128; C = 128; b -= 224; }
    else if (b < 352) { W = w5; T = t5; K = 128; C = 128; b -= 288; }
    else              { W = w6; T = t6; K = 128; C =  64; b -= 352; }
    int e = b * 256 + threadIdx.x;
    int k, n;
    if (C == 128) { k = e >> 7; n = e & 127; } else { k = e >> 6; n = e & 63; }
    T[n * K + k] = f2bf(W[e]);
}

// ---------- MFMA GEMM: out[N,COLS] = epi(A[N,K] @ W[K,COLS] * rowscale + bias) ----------
// A: bf16 [rows_pad][K] (or fp32 if A_F32, guarded); Wt: bf16 [COLS][K] transposed.
// EPI: 0=none, 1=relu, 2=sigmoid
template <int K, int COLS, int EPI, bool BIAS, bool RSCALE, bool A_F32, bool OUT_F32>
__global__ __launch_bounds__(256) void mgemm_k(
    const void* __restrict__ Av,
    const unsigned short* __restrict__ Wt,
    const float* __restrict__ bias,
    const float* __restrict__ dinv,
    void* __restrict__ outv, int nrows)
{
    constexpr int NB = COLS / 16;   // col frags per wave (8 or 4)
    constexpr int KC = K / 32;      // k chunks (4 or 2)
    const int wave = threadIdx.x >> 6;
    const int lane = threadIdx.x & 63;
    const int row0 = blockIdx.x * 64 + wave * 16;
    const int m = lane & 15;        // A-row / C-col index within frag
    const int q = lane >> 4;        // quad: k-offset q*8 (A/B), row-base q*4 (C)

    f32x4 acc[NB];
    #pragma unroll
    for (int i = 0; i < NB; i++) acc[i] = (f32x4){0.f, 0.f, 0.f, 0.f};

    const bool arow_ok = !A_F32 || (row0 + m) < nrows;

    #pragma unroll
    for (int kc = 0; kc < KC; kc++) {
        short8 af;
        if constexpr (A_F32) {
            const float* arowf = (const float*)Av + (size_t)(row0 + m) * K + q * 8 + kc * 32;
            float4 lo = make_float4(0.f, 0.f, 0.f, 0.f), hi = lo;
            if (arow_ok) { lo = *(const float4*)arowf; hi = *(const float4*)(arowf + 4); }
            af[0] = (short)f2bf(lo.x); af[1] = (short)f2bf(lo.y);
            af[2] = (short)f2bf(lo.z); af[3] = (short)f2bf(lo.w);
            af[4] = (short)f2bf(hi.x); af[5] = (short)f2bf(hi.y);
            af[6] = (short)f2bf(hi.z); af[7] = (short)f2bf(hi.w);
        } else {
            const unsigned short* arow = (const unsigned short*)Av + (size_t)(row0 + m) * K + q * 8 + kc * 32;
            af = *(const short8*)arow;
        }
        #pragma unroll
        for (int nb = 0; nb < NB; nb++) {
            short8 bf = *(const short8*)(Wt + (size_t)(nb * 16 + m) * K + kc * 32 + q * 8);
            acc[nb] = __builtin_amdgcn_mfma_f32_16x16x32_bf16(af, bf, acc[nb], 0, 0, 0);
        }
    }

    float bv[NB];
    #pragma unroll
    for (int nb = 0; nb < NB; nb++) bv[nb] = BIAS ? bias[nb * 16 + m] : 0.f;

    #pragma unroll
    for (int r = 0; r < 4; r++) {
        int row = row0 + q * 4 + r;
        if (row < nrows) {
            float sc = RSCALE ? dinv[row] : 1.f;
            #pragma unroll
            for (int nb = 0; nb < NB; nb++) {
                float t = acc[nb][r];
                if (RSCALE) t *= sc;
                t += bv[nb];
                if (EPI == 1) t = fmaxf(t, 0.f);
                if (EPI == 2) t = 1.f / (1.f + __expf(-t));
                if constexpr (OUT_F32) {
                    ((float*)outv)[(size_t)row * COLS + nb * 16 + m] = t;
                } else {
                    ((unsigned short*)outv)[(size_t)row * COLS + nb * 16 + m] = f2bf(t);
                }
            }
        }
    }
}

// ---------- GCN aggregation: out[d] = relu(dinv[d]*(hws[d] + sum_in hws[s]) + b) ----------
__global__ __launch_bounds__(256) void agg_k(
    const unsigned int* __restrict__ hws,  // [N][64] bf16x2
    const int* __restrict__ off, const int* __restrict__ csr,
    const float* __restrict__ dinv, const float* __restrict__ bias,
    unsigned int* __restrict__ out, int n)
{
    int node = blockIdx.x * 4 + (threadIdx.x >> 6);
    if (node >= n) return;
    int lane = threadIdx.x & 63;

    unsigned int v = hws[node * 64 + lane];
    float s0 = bflo(v), s1 = bfhi(v);

    int b = off[node], e = off[node + 1];
    int j = b;
    for (; j + 4 <= e; j += 4) {
        int i0 = csr[j], i1 = csr[j + 1], i2 = csr[j + 2], i3 = csr[j + 3];
        unsigned int v0 = hws[i0 * 64 + lane];
        unsigned int v1 = hws[i1 * 64 + lane];
        unsigned int v2 = hws[i2 * 64 + lane];
        unsigned int v3 = hws[i3 * 64 + lane];
        s0 += bflo(v0); s1 += bfhi(v0);
        s0 += bflo(v1); s1 += bfhi(v1);
        s0 += bflo(v2); s1 += bfhi(v2);
        s0 += bflo(v3); s1 += bfhi(v3);
    }
    for (; j < e; j++) {
        unsigned int vv = hws[csr[j] * 64 + lane];
        s0 += bflo(vv); s1 += bfhi(vv);
    }

    float di = dinv[node];
    float r0 = fmaxf(fmaf(di, s0, bias[2 * lane]), 0.f);
    float r1 = fmaxf(fmaf(di, s1, bias[2 * lane + 1]), 0.f);
    out[node * 64 + lane] = pack2(r0, r1);
}

// ---------- launch ----------
extern "C" void kernel_launch(void* const* d_in, const int* in_sizes, int n_in,
                              void* d_out, int out_size, void* d_ws, size_t ws_size,
                              hipStream_t stream)
{
    const float* x      = (const float*)d_in[0];
    const int*   ei     = (const int*)d_in[1];
    const float* enc_w1 = (const float*)d_in[2];
    const float* enc_b1 = (const float*)d_in[3];
    const float* enc_w2 = (const float*)d_in[4];
    const float* enc_b2 = (const float*)d_in[5];
    const float* w_c1   = (const float*)d_in[6];
    const float* b_c1   = (const float*)d_in[7];
    const float* w_c2   = (const float*)d_in[8];
    const float* b_c2   = (const float*)d_in[9];
    const float* w_c3   = (const float*)d_in[10];
    const float* b_c3   = (const float*)d_in[11];
    const float* dec_w1 = (const float*)d_in[12];
    const float* dec_b1 = (const float*)d_in[13];
    const float* dec_w2 = (const float*)d_in[14];
    const float* dec_b2 = (const float*)d_in[15];

    const int* src = ei;
    const int* dst = ei + NE;

    const int NP = 50048;  // rows padded to multiple of 64

    char* ws = (char*)d_ws;
    size_t o = 0;
    auto alloc = [&](size_t bytes) -> void* {
        void* p = ws + o;
        o = (o + bytes + 255) & ~(size_t)255;
        return p;
    };
    int*   cnt  = (int*)alloc((size_t)NN * 4);
    int*   cur  = (int*)alloc((size_t)NN * 4);
    int*   off  = (int*)alloc((size_t)(NN + 1) * 4);
    int*   bsum = (int*)alloc(256 * 4);
    int*   csr  = (int*)alloc((size_t)NE * 4);
    float* dinv = (float*)alloc((size_t)NN * 4);
    unsigned short* bufA = (unsigned short*)alloc((size_t)NP * HD * 2);
    unsigned short* bufB = (unsigned short*)alloc((size_t)NP * HD * 2);
    unsigned short* t0 = (unsigned short*)alloc(64 * 128 * 2);   // enc_w1^T [128][64]
    unsigned short* t1 = (unsigned short*)alloc(128 * 128 * 2);  // enc_w2^T
    unsigned short* t2 = (unsigned short*)alloc(128 * 128 * 2);  // w_c1^T
    unsigned short* t3 = (unsigned short*)alloc(128 * 128 * 2);  // w_c2^T
    unsigned short* t4 = (unsigned short*)alloc(128 * 128 * 2);  // w_c3^T
    unsigned short* t5 = (unsigned short*)alloc(128 * 128 * 2);  // dec_w1^T
    unsigned short* t6 = (unsigned short*)alloc(128 * 64 * 2);   // dec_w2^T [64][128]
    (void)ws_size; (void)n_in; (void)in_sizes; (void)out_size;

    hipMemsetAsync(cnt, 0, (size_t)NN * 4, stream);
    hipMemsetAsync(cur, 0, (size_t)NN * 4, stream);

    const int EB = (NE + 255) / 256;
    const int NB_ = (NN + 255) / 256;
    hist_k<<<EB, 256, 0, stream>>>(dst, cnt, NE);
    dinv_k<<<NB_, 256, 0, stream>>>(cnt, dinv, NN);
    scanA_k<<<NB_, 256, 0, stream>>>(cnt, off, bsum, NN);
    scanB_k<<<1, 256, 0, stream>>>(bsum, NB_);
    scanC_k<<<NB_, 256, 0, stream>>>(off, bsum, NN, NE);
    fill_k<<<EB, 256, 0, stream>>>(src, dst, off, cur, csr, NE);
    wt_k<<<384, 256, 0, stream>>>(enc_w1, enc_w2, w_c1, w_c2, w_c3, dec_w1, dec_w2,
                                  t0, t1, t2, t3, t4, t5, t6);

    const int GB = NP / 64;           // 782 row-tiles
    const int AB = (NN + 3) / 4;      // 12500 agg blocks

    // encoder
    mgemm_k<64, 128, 1, true, false, true, false><<<GB, 256, 0, stream>>>(x, t0, enc_b1, nullptr, bufA, NN);
    mgemm_k<128, 128, 0, true, false, false, false><<<GB, 256, 0, stream>>>(bufA, t1, enc_b2, nullptr, bufB, NN);
    // conv1
    mgemm_k<128, 128, 0, false, true, false, false><<<GB, 256, 0, stream>>>(bufB, t2, nullptr, dinv, bufA, NN);
    agg_k<<<AB, 256, 0, stream>>>((const unsigned int*)bufA, off, csr, dinv, b_c1, (unsigned int*)bufB, NN);
    // conv2
    mgemm_k<128, 128, 0, false, true, false, false><<<GB, 256, 0, stream>>>(bufB, t3, nullptr, dinv, bufA, NN);
    agg_k<<<AB, 256, 0, stream>>>((const unsigned int*)bufA, off, csr, dinv, b_c2, (unsigned int*)bufB, NN);
    // conv3
    mgemm_k<128, 128, 0, false, true, false, false><<<GB, 256, 0, stream>>>(bufB, t4, nullptr, dinv, bufA, NN);
    agg_k<<<AB, 256, 0, stream>>>((const unsigned int*)bufA, off, csr, dinv, b_c3, (unsigned int*)bufB, NN);
    // decoder
    mgemm_k<128, 128, 1, true, false, false, false><<<GB, 256, 0, stream>>>(bufB, t5, dec_b1, nullptr, bufA, NN);
    mgemm_k<128, 64, 2, true, false, false, true><<<GB, 256, 0, stream>>>(bufA, t6, dec_b2, nullptr, d_out, NN);
}

// Round 4
// 421.109 us; speedup vs baseline: 1.3060x; 1.0516x over previous
//
#include <hip/hip_runtime.h>
#include <stdint.h>

#define NN 50000
#define NE 800000
#define FD 64
#define HD 128

typedef __attribute__((ext_vector_type(8))) short short8;   // 8 bf16 (4 VGPRs)
typedef __attribute__((ext_vector_type(4))) float f32x4;    // MFMA acc

// ---------- bf16 helpers ----------
__device__ __forceinline__ float bflo(unsigned int v) {
    union { unsigned int u; float f; } c; c.u = v << 16; return c.f;
}
__device__ __forceinline__ float bfhi(unsigned int v) {
    union { unsigned int u; float f; } c; c.u = v & 0xffff0000u; return c.f;
}
__device__ __forceinline__ unsigned short f2bf(float f) {
    union { float f; unsigned int u; } c; c.f = f;
    unsigned int u = c.u;
    return (unsigned short)((u + 0x7fffu + ((u >> 16) & 1u)) >> 16);
}
__device__ __forceinline__ unsigned int pack2(float a, float b) {
    return (unsigned int)f2bf(a) | ((unsigned int)f2bf(b) << 16);
}

// ---------- graph prep ----------
__global__ void hist_k(const int* __restrict__ dst, int* __restrict__ cnt, int n) {
    int g = blockIdx.x * 256 + threadIdx.x;
    if (g < n) atomicAdd(&cnt[dst[g]], 1);
}

// block-level inclusive scan of cnt + dinv computation fused
__global__ void scanA_k(const int* __restrict__ cnt, int* __restrict__ off,
                        int* __restrict__ bsum, float* __restrict__ dinv, int n) {
    __shared__ int sh[256];
    int t = threadIdx.x;
    int g = blockIdx.x * 256 + t;
    int v = (g < n) ? cnt[g] : 0;
    if (g < n) dinv[g] = rsqrtf((float)(v + 1));  // +1 self-loop
    sh[t] = v; __syncthreads();
    for (int d = 1; d < 256; d <<= 1) {
        int x = (t >= d) ? sh[t - d] : 0; __syncthreads();
        sh[t] += x; __syncthreads();
    }
    if (g < n) off[g] = sh[t] - v;
    if (t == 255) bsum[blockIdx.x] = sh[255];
}

__global__ void scanB_k(int* __restrict__ bsum, int nb) {
    __shared__ int sh[256];
    int t = threadIdx.x;
    int v = (t < nb) ? bsum[t] : 0;
    sh[t] = v; __syncthreads();
    for (int d = 1; d < 256; d <<= 1) {
        int x = (t >= d) ? sh[t - d] : 0; __syncthreads();
        sh[t] += x; __syncthreads();
    }
    if (t < nb) bsum[t] = sh[t] - v;
}

__global__ void scanC_k(int* __restrict__ off, const int* __restrict__ bsum,
                        int n, int total) {
    int g = blockIdx.x * 256 + threadIdx.x;
    if (g < n) off[g] += bsum[g >> 8];
    if (g == 0) off[n] = total;
}

__global__ void fill_k(const int* __restrict__ src, const int* __restrict__ dst,
                       const int* __restrict__ off, int* __restrict__ cur,
                       unsigned short* __restrict__ csr, int n) {
    int g = blockIdx.x * 256 + threadIdx.x;
    if (g < n) {
        int d = dst[g];
        int p = atomicAdd(&cur[d], 1);
        csr[off[d] + p] = (unsigned short)src[g];  // src < 50000 < 65536
    }
}

// ---------- weight transpose+convert: W[K][C] fp32 -> Wt[C][K] bf16 ----------
__global__ void wt_k(const float* __restrict__ w0, const float* __restrict__ w1,
                     const float* __restrict__ w2, const float* __restrict__ w3,
                     const float* __restrict__ w4, const float* __restrict__ w5,
                     const float* __restrict__ w6,
                     unsigned short* __restrict__ t0, unsigned short* __restrict__ t1,
                     unsigned short* __restrict__ t2, unsigned short* __restrict__ t3,
                     unsigned short* __restrict__ t4, unsigned short* __restrict__ t5,
                     unsigned short* __restrict__ t6)
{
    int b = blockIdx.x;
    const float* W; unsigned short* T; int K, C;
    if      (b <  32) { W = w0; T = t0; K =  64; C = 128; }
    else if (b <  96) { W = w1; T = t1; K = 128; C = 128; b -= 32; }
    else if (b < 160) { W = w2; T = t2; K = 128; C = 128; b -= 96; }
    else if (b < 224) { W = w3; T = t3; K = 128; C = 128; b -= 160; }
    else if (b < 288) { W = w4; T = t4; K = 128; C = 128; b -= 224; }
    else if (b < 352) { W = w5; T = t5; K = 128; C = 128; b -= 288; }
    else              { W = w6; T = t6; K = 128; C =  64; b -= 352; }
    int e = b * 256 + threadIdx.x;
    int k, n;
    if (C == 128) { k = e >> 7; n = e & 127; } else { k = e >> 6; n = e & 63; }
    T[n * K + k] = f2bf(W[e]);
}

// ---------- MFMA GEMM: out[N,COLS] = epi(A[N,K] @ W[K,COLS] * rowscale + bias) ----------
// A: bf16 [rows_pad][K] (or fp32 if A_F32, guarded); Wt: bf16 [COLS][K] transposed.
// EPI: 0=none, 1=relu, 2=sigmoid
template <int K, int COLS, int EPI, bool BIAS, bool RSCALE, bool A_F32, bool OUT_F32>
__global__ __launch_bounds__(256) void mgemm_k(
    const void* __restrict__ Av,
    const unsigned short* __restrict__ Wt,
    const float* __restrict__ bias,
    const float* __restrict__ dinv,
    void* __restrict__ outv, int nrows)
{
    constexpr int NB = COLS / 16;   // col frags per wave (8 or 4)
    constexpr int KC = K / 32;      // k chunks (4 or 2)
    const int wave = threadIdx.x >> 6;
    const int lane = threadIdx.x & 63;
    const int row0 = blockIdx.x * 64 + wave * 16;
    const int m = lane & 15;        // A-row / C-col index within frag
    const int q = lane >> 4;        // quad: k-offset q*8 (A/B), row-base q*4 (C)

    f32x4 acc[NB];
    #pragma unroll
    for (int i = 0; i < NB; i++) acc[i] = (f32x4){0.f, 0.f, 0.f, 0.f};

    const bool arow_ok = !A_F32 || (row0 + m) < nrows;

    #pragma unroll
    for (int kc = 0; kc < KC; kc++) {
        short8 af;
        if constexpr (A_F32) {
            const float* arowf = (const float*)Av + (size_t)(row0 + m) * K + q * 8 + kc * 32;
            float4 lo = make_float4(0.f, 0.f, 0.f, 0.f), hi = lo;
            if (arow_ok) { lo = *(const float4*)arowf; hi = *(const float4*)(arowf + 4); }
            af[0] = (short)f2bf(lo.x); af[1] = (short)f2bf(lo.y);
            af[2] = (short)f2bf(lo.z); af[3] = (short)f2bf(lo.w);
            af[4] = (short)f2bf(hi.x); af[5] = (short)f2bf(hi.y);
            af[6] = (short)f2bf(hi.z); af[7] = (short)f2bf(hi.w);
        } else {
            const unsigned short* arow = (const unsigned short*)Av + (size_t)(row0 + m) * K + q * 8 + kc * 32;
            af = *(const short8*)arow;
        }
        #pragma unroll
        for (int nb = 0; nb < NB; nb++) {
            short8 bf = *(const short8*)(Wt + (size_t)(nb * 16 + m) * K + kc * 32 + q * 8);
            acc[nb] = __builtin_amdgcn_mfma_f32_16x16x32_bf16(af, bf, acc[nb], 0, 0, 0);
        }
    }

    float bv[NB];
    #pragma unroll
    for (int nb = 0; nb < NB; nb++) bv[nb] = BIAS ? bias[nb * 16 + m] : 0.f;

    #pragma unroll
    for (int r = 0; r < 4; r++) {
        int row = row0 + q * 4 + r;
        if (row < nrows) {
            float sc = RSCALE ? dinv[row] : 1.f;
            #pragma unroll
            for (int nb = 0; nb < NB; nb++) {
                float t = acc[nb][r];
                if (RSCALE) t *= sc;
                t += bv[nb];
                if (EPI == 1) t = fmaxf(t, 0.f);
                if (EPI == 2) t = 1.f / (1.f + __expf(-t));
                if constexpr (OUT_F32) {
                    ((float*)outv)[(size_t)row * COLS + nb * 16 + m] = t;
                } else {
                    ((unsigned short*)outv)[(size_t)row * COLS + nb * 16 + m] = f2bf(t);
                }
            }
        }
    }
}

// ---------- GCN aggregation: out[d] = relu(dinv[d]*(hws[d] + sum_in hws[s]) + b) ----------
// half-wave (32 lanes) per node; lane owns features {4l..4l+3} as uint2 (bf16x4)
__global__ __launch_bounds__(256) void agg_k(
    const uint2* __restrict__ hws,  // [N][32] uint2
    const int* __restrict__ off, const unsigned short* __restrict__ csr,
    const float* __restrict__ dinv, const float* __restrict__ bias,
    uint2* __restrict__ out, int n)
{
    int node = blockIdx.x * 8 + (threadIdx.x >> 5);
    if (node >= n) return;
    int lane = threadIdx.x & 31;

    uint2 v = hws[node * 32 + lane];  // self-loop term
    float s0 = bflo(v.x), s1 = bfhi(v.x), s2 = bflo(v.y), s3 = bfhi(v.y);

    int b = off[node], e = off[node + 1];
    int j = b;
    for (; j + 8 <= e; j += 8) {
        uint2 t[8];
        #pragma unroll
        for (int u = 0; u < 8; u++) t[u] = hws[(int)csr[j + u] * 32 + lane];
        #pragma unroll
        for (int u = 0; u < 8; u++) {
            s0 += bflo(t[u].x); s1 += bfhi(t[u].x);
            s2 += bflo(t[u].y); s3 += bfhi(t[u].y);
        }
    }
    for (; j < e; j++) {
        uint2 t = hws[(int)csr[j] * 32 + lane];
        s0 += bflo(t.x); s1 += bfhi(t.x);
        s2 += bflo(t.y); s3 += bfhi(t.y);
    }

    float di = dinv[node];
    float4 bv = *(const float4*)(bias + 4 * lane);
    float r0 = fmaxf(fmaf(di, s0, bv.x), 0.f);
    float r1 = fmaxf(fmaf(di, s1, bv.y), 0.f);
    float r2 = fmaxf(fmaf(di, s2, bv.z), 0.f);
    float r3 = fmaxf(fmaf(di, s3, bv.w), 0.f);
    uint2 o; o.x = pack2(r0, r1); o.y = pack2(r2, r3);
    out[node * 32 + lane] = o;
}

// ---------- launch ----------
extern "C" void kernel_launch(void* const* d_in, const int* in_sizes, int n_in,
                              void* d_out, int out_size, void* d_ws, size_t ws_size,
                              hipStream_t stream)
{
    const float* x      = (const float*)d_in[0];
    const int*   ei     = (const int*)d_in[1];
    const float* enc_w1 = (const float*)d_in[2];
    const float* enc_b1 = (const float*)d_in[3];
    const float* enc_w2 = (const float*)d_in[4];
    const float* enc_b2 = (const float*)d_in[5];
    const float* w_c1   = (const float*)d_in[6];
    const float* b_c1   = (const float*)d_in[7];
    const float* w_c2   = (const float*)d_in[8];
    const float* b_c2   = (const float*)d_in[9];
    const float* w_c3   = (const float*)d_in[10];
    const float* b_c3   = (const float*)d_in[11];
    const float* dec_w1 = (const float*)d_in[12];
    const float* dec_b1 = (const float*)d_in[13];
    const float* dec_w2 = (const float*)d_in[14];
    const float* dec_b2 = (const float*)d_in[15];

    const int* src = ei;
    const int* dst = ei + NE;

    const int NP = 50048;  // rows padded to multiple of 64

    char* ws = (char*)d_ws;
    size_t o = 0;
    auto alloc = [&](size_t bytes) -> void* {
        void* p = ws + o;
        o = (o + bytes + 255) & ~(size_t)255;
        return p;
    };
    int*   cnt  = (int*)alloc((size_t)NN * 4);
    int*   cur  = (int*)alloc((size_t)NN * 4);
    int*   off  = (int*)alloc((size_t)(NN + 1) * 4);
    int*   bsum = (int*)alloc(256 * 4);
    unsigned short* csr = (unsigned short*)alloc((size_t)NE * 2);
    float* dinv = (float*)alloc((size_t)NN * 4);
    unsigned short* bufA = (unsigned short*)alloc((size_t)NP * HD * 2);
    unsigned short* bufB = (unsigned short*)alloc((size_t)NP * HD * 2);
    unsigned short* t0 = (unsigned short*)alloc(64 * 128 * 2);   // enc_w1^T
    unsigned short* t1 = (unsigned short*)alloc(128 * 128 * 2);  // enc_w2^T
    unsigned short* t2 = (unsigned short*)alloc(128 * 128 * 2);  // w_c1^T
    unsigned short* t3 = (unsigned short*)alloc(128 * 128 * 2);  // w_c2^T
    unsigned short* t4 = (unsigned short*)alloc(128 * 128 * 2);  // w_c3^T
    unsigned short* t5 = (unsigned short*)alloc(128 * 128 * 2);  // dec_w1^T
    unsigned short* t6 = (unsigned short*)alloc(128 * 64 * 2);   // dec_w2^T
    (void)ws_size; (void)n_in; (void)in_sizes; (void)out_size;

    hipMemsetAsync(cnt, 0, (size_t)NN * 4, stream);
    hipMemsetAsync(cur, 0, (size_t)NN * 4, stream);

    const int EB = (NE + 255) / 256;
    const int NB_ = (NN + 255) / 256;
    hist_k<<<EB, 256, 0, stream>>>(dst, cnt, NE);
    scanA_k<<<NB_, 256, 0, stream>>>(cnt, off, bsum, dinv, NN);
    scanB_k<<<1, 256, 0, stream>>>(bsum, NB_);
    scanC_k<<<NB_, 256, 0, stream>>>(off, bsum, NN, NE);
    fill_k<<<EB, 256, 0, stream>>>(src, dst, off, cur, csr, NE);
    wt_k<<<384, 256, 0, stream>>>(enc_w1, enc_w2, w_c1, w_c2, w_c3, dec_w1, dec_w2,
                                  t0, t1, t2, t3, t4, t5, t6);

    const int GB = NP / 64;           // 782 row-tiles
    const int AB = (NN + 7) / 8;      // 6250 agg blocks

    // encoder
    mgemm_k<64, 128, 1, true, false, true, false><<<GB, 256, 0, stream>>>(x, t0, enc_b1, nullptr, bufA, NN);
    mgemm_k<128, 128, 0, true, false, false, false><<<GB, 256, 0, stream>>>(bufA, t1, enc_b2, nullptr, bufB, NN);
    // conv1
    mgemm_k<128, 128, 0, false, true, false, false><<<GB, 256, 0, stream>>>(bufB, t2, nullptr, dinv, bufA, NN);
    agg_k<<<AB, 256, 0, stream>>>((const uint2*)bufA, off, csr, dinv, b_c1, (uint2*)bufB, NN);
    // conv2
    mgemm_k<128, 128, 0, false, true, false, false><<<GB, 256, 0, stream>>>(bufB, t3, nullptr, dinv, bufA, NN);
    agg_k<<<AB, 256, 0, stream>>>((const uint2*)bufA, off, csr, dinv, b_c2, (uint2*)bufB, NN);
    // conv3
    mgemm_k<128, 128, 0, false, true, false, false><<<GB, 256, 0, stream>>>(bufB, t4, nullptr, dinv, bufA, NN);
    agg_k<<<AB, 256, 0, stream>>>((const uint2*)bufA, off, csr, dinv, b_c3, (uint2*)bufB, NN);
    // decoder
    mgemm_k<128, 128, 1, true, false, false, false><<<GB, 256, 0, stream>>>(bufB, t5, dec_b1, nullptr, bufA, NN);
    mgemm_k<128, 64, 2, true, false, false, true><<<GB, 256, 0, stream>>>(bufA, t6, dec_b2, nullptr, d_out, NN);
}

// Round 5
// 347.807 us; speedup vs baseline: 1.5813x; 1.2108x over previous
//
#include <hip/hip_runtime.h>
#include <stdint.h>

#define NN 50000
#define NE 800000
#define FD 64
#define HD 128

typedef __attribute__((ext_vector_type(8))) short short8;   // 8 bf16 (4 VGPRs)
typedef __attribute__((ext_vector_type(4))) float f32x4;    // MFMA acc

// ---------- bf16 helpers ----------
__device__ __forceinline__ float bflo(unsigned int v) {
    union { unsigned int u; float f; } c; c.u = v << 16; return c.f;
}
__device__ __forceinline__ float bfhi(unsigned int v) {
    union { unsigned int u; float f; } c; c.u = v & 0xffff0000u; return c.f;
}
__device__ __forceinline__ unsigned short f2bf(float f) {
    union { float f; unsigned int u; } c; c.f = f;
    unsigned int u = c.u;
    return (unsigned short)((u + 0x7fffu + ((u >> 16) & 1u)) >> 16);
}
__device__ __forceinline__ unsigned int pack2(float a, float b) {
    return (unsigned int)f2bf(a) | ((unsigned int)f2bf(b) << 16);
}

// ---------- graph prep ----------
__global__ void hist_k(const int* __restrict__ dst, int* __restrict__ cnt, int n) {
    int g = blockIdx.x * 256 + threadIdx.x;
    if (g < n) atomicAdd(&cnt[dst[g]], 1);
}

// block-level exclusive scan of cnt + dinv fused
__global__ void scanA_k(const int* __restrict__ cnt, int* __restrict__ off,
                        int* __restrict__ bsum, float* __restrict__ dinv, int n) {
    __shared__ int sh[256];
    int t = threadIdx.x;
    int g = blockIdx.x * 256 + t;
    int v = (g < n) ? cnt[g] : 0;
    if (g < n) dinv[g] = rsqrtf((float)(v + 1));  // +1 self-loop
    sh[t] = v; __syncthreads();
    for (int d = 1; d < 256; d <<= 1) {
        int x = (t >= d) ? sh[t - d] : 0; __syncthreads();
        sh[t] += x; __syncthreads();
    }
    if (g < n) off[g] = sh[t] - v;
    if (t == 255) bsum[blockIdx.x] = sh[255];
}

__global__ void scanB_k(int* __restrict__ bsum, int nb) {
    __shared__ int sh[256];
    int t = threadIdx.x;
    int v = (t < nb) ? bsum[t] : 0;
    sh[t] = v; __syncthreads();
    for (int d = 1; d < 256; d <<= 1) {
        int x = (t >= d) ? sh[t - d] : 0; __syncthreads();
        sh[t] += x; __syncthreads();
    }
    if (t < nb) bsum[t] = sh[t] - v;
}

// CSR fill; final offset = off[d] + bsum[d>>8] computed inline (scanC folded away)
__global__ void fill_k(const int* __restrict__ src, const int* __restrict__ dst,
                       const int* __restrict__ off, const int* __restrict__ bsum,
                       int* __restrict__ cur, unsigned short* __restrict__ csr, int n) {
    int g = blockIdx.x * 256 + threadIdx.x;
    if (g < n) {
        int d = dst[g];
        int p = atomicAdd(&cur[d], 1);
        csr[off[d] + bsum[d >> 8] + p] = (unsigned short)src[g];
    }
}

// ---------- weight transpose+convert: W[K][C] fp32 -> Wt[C][K] bf16 ----------
__global__ void wt_k(const float* __restrict__ w0, const float* __restrict__ w1,
                     const float* __restrict__ w2, const float* __restrict__ w3,
                     const float* __restrict__ w4, const float* __restrict__ w5,
                     const float* __restrict__ w6,
                     unsigned short* __restrict__ t0, unsigned short* __restrict__ t1,
                     unsigned short* __restrict__ t2, unsigned short* __restrict__ t3,
                     unsigned short* __restrict__ t4, unsigned short* __restrict__ t5,
                     unsigned short* __restrict__ t6)
{
    int b = blockIdx.x;
    const float* W; unsigned short* T; int K, C;
    if      (b <  32) { W = w0; T = t0; K =  64; C = 128; }
    else if (b <  96) { W = w1; T = t1; K = 128; C = 128; b -= 32; }
    else if (b < 160) { W = w2; T = t2; K = 128; C = 128; b -= 96; }
    else if (b < 224) { W = w3; T = t3; K = 128; C = 128; b -= 160; }
    else if (b < 288) { W = w4; T = t4; K = 128; C = 128; b -= 224; }
    else if (b < 352) { W = w5; T = t5; K = 128; C = 128; b -= 288; }
    else              { W = w6; T = t6; K = 128; C =  64; b -= 352; }
    int e = b * 256 + threadIdx.x;
    int k, n;
    if (C == 128) { k = e >> 7; n = e & 127; } else { k = e >> 6; n = e & 63; }
    T[n * K + k] = f2bf(W[e]);
}

// ---------- MFMA GEMM: out[N,COLS] = epi(A[N,K] @ W[K,COLS] * rowscale + bias) ----------
// Wt [COLS][K] bf16 staged to LDS once per block; B-frags via ds_read_b128.
// LDS row stride K+8 (272 B @ K=128): bank index advances 4*m mod 32 -> 2-way only (free).
// EPI: 0=none, 1=relu, 2=sigmoid
template <int K, int COLS, int EPI, bool BIAS, bool RSCALE, bool A_F32, bool OUT_F32>
__global__ __launch_bounds__(256) void mgemm_k(
    const void* __restrict__ Av,
    const unsigned short* __restrict__ Wt,
    const float* __restrict__ bias,
    const float* __restrict__ dinv,
    void* __restrict__ outv, int nrows)
{
    constexpr int NB = COLS / 16;   // col frags per wave (8 or 4)
    constexpr int KC = K / 32;      // k chunks (4 or 2)
    constexpr int LP = K + 8;       // padded LDS row stride (elements)
    __shared__ unsigned short Ws[COLS * LP];

    const int tid = threadIdx.x;
    // stage Wt -> LDS (uint4 = 8 bf16 per copy)
    {
        constexpr int NV = COLS * K / 8;   // uint4 count
        constexpr int RV = K / 8;          // uint4 per row
        #pragma unroll
        for (int i = tid; i < NV; i += 256) {
            int c = i / RV, kv = i % RV;
            *(uint4*)&Ws[c * LP + kv * 8] = *(const uint4*)(Wt + (size_t)c * K + kv * 8);
        }
    }

    const int wave = tid >> 6;
    const int lane = tid & 63;
    const int row0 = blockIdx.x * 64 + wave * 16;
    const int m = lane & 15;        // A-row / C-col index within frag
    const int q = lane >> 4;        // quad: k-offset q*8 (A/B), row-base q*4 (C)

    f32x4 acc[NB];
    #pragma unroll
    for (int i = 0; i < NB; i++) acc[i] = (f32x4){0.f, 0.f, 0.f, 0.f};

    const bool arow_ok = !A_F32 || (row0 + m) < nrows;

    // prefetch A frags (independent of LDS staging)
    short8 af[KC];
    #pragma unroll
    for (int kc = 0; kc < KC; kc++) {
        if constexpr (A_F32) {
            const float* arowf = (const float*)Av + (size_t)(row0 + m) * K + q * 8 + kc * 32;
            float4 lo = make_float4(0.f, 0.f, 0.f, 0.f), hi = lo;
            if (arow_ok) { lo = *(const float4*)arowf; hi = *(const float4*)(arowf + 4); }
            af[kc][0] = (short)f2bf(lo.x); af[kc][1] = (short)f2bf(lo.y);
            af[kc][2] = (short)f2bf(lo.z); af[kc][3] = (short)f2bf(lo.w);
            af[kc][4] = (short)f2bf(hi.x); af[kc][5] = (short)f2bf(hi.y);
            af[kc][6] = (short)f2bf(hi.z); af[kc][7] = (short)f2bf(hi.w);
        } else {
            const unsigned short* arow = (const unsigned short*)Av + (size_t)(row0 + m) * K + q * 8 + kc * 32;
            af[kc] = *(const short8*)arow;
        }
    }
    __syncthreads();

    #pragma unroll
    for (int kc = 0; kc < KC; kc++) {
        #pragma unroll
        for (int nb = 0; nb < NB; nb++) {
            short8 bf = *(const short8*)&Ws[(nb * 16 + m) * LP + kc * 32 + q * 8];
            acc[nb] = __builtin_amdgcn_mfma_f32_16x16x32_bf16(af[kc], bf, acc[nb], 0, 0, 0);
        }
    }

    float bv[NB];
    #pragma unroll
    for (int nb = 0; nb < NB; nb++) bv[nb] = BIAS ? bias[nb * 16 + m] : 0.f;

    #pragma unroll
    for (int r = 0; r < 4; r++) {
        int row = row0 + q * 4 + r;
        if (row < nrows) {
            float sc = RSCALE ? dinv[row] : 1.f;
            #pragma unroll
            for (int nb = 0; nb < NB; nb++) {
                float t = acc[nb][r];
                if (RSCALE) t *= sc;
                t += bv[nb];
                if (EPI == 1) t = fmaxf(t, 0.f);
                if (EPI == 2) t = 1.f / (1.f + __expf(-t));
                if constexpr (OUT_F32) {
                    ((float*)outv)[(size_t)row * COLS + nb * 16 + m] = t;
                } else {
                    ((unsigned short*)outv)[(size_t)row * COLS + nb * 16 + m] = f2bf(t);
                }
            }
        }
    }
}

// ---------- GCN aggregation: out[d] = relu(dinv[d]*(hws[d] + sum_in hws[s]) + b) ----------
// half-wave (32 lanes) per node; lane owns features {4l..4l+3} as uint2 (bf16x4)
__global__ __launch_bounds__(256) void agg_k(
    const uint2* __restrict__ hws,  // [N][32] uint2
    const int* __restrict__ off, const int* __restrict__ bsum,
    const unsigned short* __restrict__ csr,
    const float* __restrict__ dinv, const float* __restrict__ bias,
    uint2* __restrict__ out, int n)
{
    int node = blockIdx.x * 8 + (threadIdx.x >> 5);
    if (node >= n) return;
    int lane = threadIdx.x & 31;

    uint2 v = hws[node * 32 + lane];  // self-loop term
    float s0 = bflo(v.x), s1 = bfhi(v.x), s2 = bflo(v.y), s3 = bfhi(v.y);

    int b = off[node] + bsum[node >> 8];
    int e = (node + 1 < n) ? (off[node + 1] + bsum[(node + 1) >> 8]) : NE;
    int j = b;
    for (; j + 8 <= e; j += 8) {
        uint2 t[8];
        #pragma unroll
        for (int u = 0; u < 8; u++) t[u] = hws[(int)csr[j + u] * 32 + lane];
        #pragma unroll
        for (int u = 0; u < 8; u++) {
            s0 += bflo(t[u].x); s1 += bfhi(t[u].x);
            s2 += bflo(t[u].y); s3 += bfhi(t[u].y);
        }
    }
    for (; j < e; j++) {
        uint2 t = hws[(int)csr[j] * 32 + lane];
        s0 += bflo(t.x); s1 += bfhi(t.x);
        s2 += bflo(t.y); s3 += bfhi(t.y);
    }

    float di = dinv[node];
    float4 bv = *(const float4*)(bias + 4 * lane);
    float r0 = fmaxf(fmaf(di, s0, bv.x), 0.f);
    float r1 = fmaxf(fmaf(di, s1, bv.y), 0.f);
    float r2 = fmaxf(fmaf(di, s2, bv.z), 0.f);
    float r3 = fmaxf(fmaf(di, s3, bv.w), 0.f);
    uint2 o; o.x = pack2(r0, r1); o.y = pack2(r2, r3);
    out[node * 32 + lane] = o;
}

// ---------- launch ----------
extern "C" void kernel_launch(void* const* d_in, const int* in_sizes, int n_in,
                              void* d_out, int out_size, void* d_ws, size_t ws_size,
                              hipStream_t stream)
{
    const float* x      = (const float*)d_in[0];
    const int*   ei     = (const int*)d_in[1];
    const float* enc_w1 = (const float*)d_in[2];
    const float* enc_b1 = (const float*)d_in[3];
    const float* enc_w2 = (const float*)d_in[4];
    const float* enc_b2 = (const float*)d_in[5];
    const float* w_c1   = (const float*)d_in[6];
    const float* b_c1   = (const float*)d_in[7];
    const float* w_c2   = (const float*)d_in[8];
    const float* b_c2   = (const float*)d_in[9];
    const float* w_c3   = (const float*)d_in[10];
    const float* b_c3   = (const float*)d_in[11];
    const float* dec_w1 = (const float*)d_in[12];
    const float* dec_b1 = (const float*)d_in[13];
    const float* dec_w2 = (const float*)d_in[14];
    const float* dec_b2 = (const float*)d_in[15];

    const int* src = ei;
    const int* dst = ei + NE;

    const int NP = 50048;  // rows padded to multiple of 64

    char* ws = (char*)d_ws;
    size_t o = 0;
    auto alloc = [&](size_t bytes) -> void* {
        void* p = ws + o;
        o = (o + bytes + 255) & ~(size_t)255;
        return p;
    };
    int*   cnt  = (int*)alloc((size_t)NN * 4);
    int*   cur  = (int*)alloc((size_t)NN * 4);
    int*   off  = (int*)alloc((size_t)(NN + 1) * 4);
    int*   bsum = (int*)alloc(256 * 4);
    unsigned short* csr = (unsigned short*)alloc((size_t)NE * 2);
    float* dinv = (float*)alloc((size_t)NN * 4);
    unsigned short* bufA = (unsigned short*)alloc((size_t)NP * HD * 2);
    unsigned short* bufB = (unsigned short*)alloc((size_t)NP * HD * 2);
    unsigned short* t0 = (unsigned short*)alloc(64 * 128 * 2);   // enc_w1^T
    unsigned short* t1 = (unsigned short*)alloc(128 * 128 * 2);  // enc_w2^T
    unsigned short* t2 = (unsigned short*)alloc(128 * 128 * 2);  // w_c1^T
    unsigned short* t3 = (unsigned short*)alloc(128 * 128 * 2);  // w_c2^T
    unsigned short* t4 = (unsigned short*)alloc(128 * 128 * 2);  // w_c3^T
    unsigned short* t5 = (unsigned short*)alloc(128 * 128 * 2);  // dec_w1^T
    unsigned short* t6 = (unsigned short*)alloc(128 * 64 * 2);   // dec_w2^T
    (void)ws_size; (void)n_in; (void)in_sizes; (void)out_size;

    hipMemsetAsync(cnt, 0, (size_t)NN * 4, stream);
    hipMemsetAsync(cur, 0, (size_t)NN * 4, stream);

    const int EB = (NE + 255) / 256;
    const int NB_ = (NN + 255) / 256;
    hist_k<<<EB, 256, 0, stream>>>(dst, cnt, NE);
    scanA_k<<<NB_, 256, 0, stream>>>(cnt, off, bsum, dinv, NN);
    scanB_k<<<1, 256, 0, stream>>>(bsum, NB_);
    fill_k<<<EB, 256, 0, stream>>>(src, dst, off, bsum, cur, csr, NE);
    wt_k<<<384, 256, 0, stream>>>(enc_w1, enc_w2, w_c1, w_c2, w_c3, dec_w1, dec_w2,
                                  t0, t1, t2, t3, t4, t5, t6);

    const int GB = NP / 64;           // 782 row-tiles
    const int AB = (NN + 7) / 8;      // 6250 agg blocks

    // encoder
    mgemm_k<64, 128, 1, true, false, true, false><<<GB, 256, 0, stream>>>(x, t0, enc_b1, nullptr, bufA, NN);
    mgemm_k<128, 128, 0, true, false, false, false><<<GB, 256, 0, stream>>>(bufA, t1, enc_b2, nullptr, bufB, NN);
    // conv1
    mgemm_k<128, 128, 0, false, true, false, false><<<GB, 256, 0, stream>>>(bufB, t2, nullptr, dinv, bufA, NN);
    agg_k<<<AB, 256, 0, stream>>>((const uint2*)bufA, off, bsum, csr, dinv, b_c1, (uint2*)bufB, NN);
    // conv2
    mgemm_k<128, 128, 0, false, true, false, false><<<GB, 256, 0, stream>>>(bufB, t3, nullptr, dinv, bufA, NN);
    agg_k<<<AB, 256, 0, stream>>>((const uint2*)bufA, off, bsum, csr, dinv, b_c2, (uint2*)bufB, NN);
    // conv3
    mgemm_k<128, 128, 0, false, true, false, false><<<GB, 256, 0, stream>>>(bufB, t4, nullptr, dinv, bufA, NN);
    agg_k<<<AB, 256, 0, stream>>>((const uint2*)bufA, off, bsum, csr, dinv, b_c3, (uint2*)bufB, NN);
    // decoder
    mgemm_k<128, 128, 1, true, false, false, false><<<GB, 256, 0, stream>>>(bufB, t5, dec_b1, nullptr, bufA, NN);
    mgemm_k<128, 64, 2, true, false, false, true><<<GB, 256, 0, stream>>>(bufA, t6, dec_b2, nullptr, d_out, NN);
}